// Round 2
// baseline (980.187 us; speedup 1.0000x reference)
//
#include <hip/hip_runtime.h>
#include <math.h>

#define N_ROWS 16384
#define N_EXP  256
#define K_DIM  7168
#define BM 64
#define BN 64
#define BK 32
#define KITERS (K_DIM / BK)   // 224
#define K2 (K_DIM * 2)        // halves per expert row in Wint

typedef __attribute__((ext_vector_type(4))) float     f32x4;
typedef __attribute__((ext_vector_type(8))) _Float16  f16x8;

// split 8 fp32 values (scaled) into fp16 hi + fp16 residual fragments
__device__ __forceinline__ void split8(const float4 u, const float4 v, const float scale,
                                       f16x8& h, f16x8& l) {
  float f[8] = {u.x, u.y, u.z, u.w, v.x, v.y, v.z, v.w};
#pragma unroll
  for (int t = 0; t < 8; ++t) {
    const float sv = f[t] * scale;
    const _Float16 hh = (_Float16)sv;        // RN
    h[t] = hh;
    l[t] = (_Float16)(sv - (float)hh);       // exact fp32 residual, then RN to fp16
  }
}

// one-time W pre-split into INTERLEAVED layout:
// Wint[e][octet o][0..7] = hi(64*W[e][8o..8o+7]), [8..15] = lo residual.
// One thread per octet: E*K/8 = 229376 threads.
__global__ __launch_bounds__(256) void wsplit_kernel(const float* __restrict__ W,
                                                     _Float16* __restrict__ Wint) {
  const int idx = blockIdx.x * 256 + threadIdx.x;
  const int e = idx / (K_DIM / 8);
  const int o = idx % (K_DIM / 8);
  const float4* p = (const float4*)(W + (size_t)e * K_DIM + o * 8);
  f16x8 h, l;
  split8(p[0], p[1], 64.0f, h, l);
  _Float16* dst = Wint + (size_t)e * K2 + o * 16;
  *(f16x8*)dst       = h;
  *(f16x8*)(dst + 8) = l;
}

// C[m][e] = sigmoid( (1/1024) * sum_k (16*x[m][k]) * (64*W[e][k]) ), fp16-split 3-term MFMA.
//
// W path: NO LDS — per-wave direct global->reg f16x8 loads from Wint (interleaved hi/lo,
//   one 128B line per expert-row per K-step; colBlk = bid&3 pins each XCD to one 1.84MB
//   W slice -> L2-resident).
// X path: reg-stage fp32 -> split8 once (no redundancy) -> LDS fp16, row-major
//   [row][8 chunks of 16B] with chunk slot (2o+h)^(row&7): both ds_write_b128 and
//   ds_read_b128 touch each 16B bank-slot with exactly 8 lanes = conflict-free.
// Single barrier per K-iter, 1-deep X prefetch, grid 1024 -> 4 blocks/CU (16 waves/CU).
__global__ __launch_bounds__(256, 4) void gemm_sig_kernel(const float* __restrict__ X,
                                                          const _Float16* __restrict__ Wint,
                                                          float* __restrict__ S) {
  __shared__ _Float16 sX[2][BM * BK * 2];   // 2 x 8 KB

  const int tid  = threadIdx.x;
  const int lane = tid & 63;
  const int wave = tid >> 6;
  const int wr   = wave & 1;      // row half: 32 rows
  const int wc   = wave >> 1;     // col half: 32 cols
  const int ml   = lane & 15;
  const int quad = lane >> 4;

  // colBlk = bid&3: blocks b, b+8, b+16.. on XCD (b&7) share one colBlk -> W L2-local.
  // rowBlk stripes are each consumed by 4 colBlks; LLC absorbs the X re-reads.
  const int    colBlk  = blockIdx.x & 3;
  const int    rowBlk  = blockIdx.x >> 2;
  const size_t rowBase = (size_t)rowBlk * BM;
  const int    colBase = colBlk * BN;

  // X staging role: thread t -> row sr = t>>2, octet so = t&3 (8 consecutive k)
  const int    sr   = tid >> 2;
  const int    so   = tid & 3;
  const float* xsrc = X + (rowBase + (size_t)sr) * K_DIM + so * 8;
  const int    wslot_h = sr * 8 + ((2 * so)     ^ (sr & 7));
  const int    wslot_l = sr * 8 + ((2 * so + 1) ^ (sr & 7));

  // B-frag lane pointers: row = colBase + wc*32 + tn*16 + ml, k-octet = quad
  const _Float16* wp[2];
#pragma unroll
  for (int tn = 0; tn < 2; ++tn)
    wp[tn] = Wint + (size_t)(colBase + wc * 32 + tn * 16 + ml) * K2 + quad * 16;

  // A-frag LDS offsets (halves): row = wr*32 + tm*16 + ml
  int xoff_h[2], xoff_l[2];
#pragma unroll
  for (int tm = 0; tm < 2; ++tm) {
    const int row = wr * 32 + tm * 16 + ml;
    const int sw  = row & 7;
    xoff_h[tm] = (row * 8 + ((2 * quad)     ^ sw)) * 8;
    xoff_l[tm] = (row * 8 + ((2 * quad + 1) ^ sw)) * 8;
  }

  f32x4 acc[2][2];
#pragma unroll
  for (int a = 0; a < 2; ++a)
#pragma unroll
    for (int b = 0; b < 2; ++b) acc[a][b] = (f32x4){0.f, 0.f, 0.f, 0.f};

  // prologue: stage tile 0
  {
    const float4 u = *(const float4*)xsrc;
    const float4 v = *(const float4*)(xsrc + 4);
    f16x8 h, l;
    split8(u, v, 16.0f, h, l);
    *(f16x8*)&sX[0][wslot_h * 8] = h;
    *(f16x8*)&sX[0][wslot_l * 8] = l;
  }
  asm volatile("s_waitcnt lgkmcnt(0)" ::: "memory");
  __builtin_amdgcn_s_barrier();
  asm volatile("" ::: "memory");

  for (int kb = 0; kb < KITERS; ++kb) {
    const int cur = kb & 1;

    // issue next X tile loads early (latency hides under W loads + ds reads + MFMA)
    float4 nu = {0.f, 0.f, 0.f, 0.f}, nv = {0.f, 0.f, 0.f, 0.f};
    if (kb + 1 < KITERS) {
      const float* nx = xsrc + (kb + 1) * BK;
      nu = *(const float4*)nx;
      nv = *(const float4*)(nx + 4);
    }

    // B fragments direct from global (L2): one 128B line per expert row, bh/bl share it
    f16x8 bh[2], bl[2];
#pragma unroll
    for (int tn = 0; tn < 2; ++tn) {
      const _Float16* q = wp[tn] + (size_t)kb * 64;
      bh[tn] = *(const f16x8*)q;
      bl[tn] = *(const f16x8*)(q + 8);
    }

    // A fragments from LDS
    f16x8 ah[2], al[2];
#pragma unroll
    for (int tm = 0; tm < 2; ++tm) {
      ah[tm] = *(const f16x8*)&sX[cur][xoff_h[tm]];
      al[tm] = *(const f16x8*)&sX[cur][xoff_l[tm]];
    }

#pragma unroll
    for (int tm = 0; tm < 2; ++tm)
#pragma unroll
      for (int tn = 0; tn < 2; ++tn) {
        acc[tm][tn] = __builtin_amdgcn_mfma_f32_16x16x32_f16(ah[tm], bh[tn], acc[tm][tn], 0, 0, 0);
        acc[tm][tn] = __builtin_amdgcn_mfma_f32_16x16x32_f16(ah[tm], bl[tn], acc[tm][tn], 0, 0, 0);
        acc[tm][tn] = __builtin_amdgcn_mfma_f32_16x16x32_f16(al[tm], bh[tn], acc[tm][tn], 0, 0, 0);
      }

    // stage next tile into the other buffer (other waves are reading sX[cur] only)
    if (kb + 1 < KITERS) {
      f16x8 h, l;
      split8(nu, nv, 16.0f, h, l);
      *(f16x8*)&sX[cur ^ 1][wslot_h * 8] = h;
      *(f16x8*)&sX[cur ^ 1][wslot_l * 8] = l;
    }

    asm volatile("s_waitcnt lgkmcnt(0)" ::: "memory");
    __builtin_amdgcn_s_barrier();
    asm volatile("" ::: "memory");
  }

  // epilogue: descale + sigmoid, store scores. C/D: col=lane&15, row=(lane>>4)*4+reg
  const float inv = 1.0f / 1024.0f;
#pragma unroll
  for (int tm = 0; tm < 2; ++tm)
#pragma unroll
    for (int tn = 0; tn < 2; ++tn)
#pragma unroll
      for (int rg = 0; rg < 4; ++rg) {
        const size_t r = rowBase + wr * 32 + tm * 16 + quad * 4 + rg;
        const int    c = colBase + wc * 32 + tn * 16 + ml;
        const float  z = acc[tm][tn][rg] * inv;
        S[r * N_EXP + c] = 1.0f / (1.0f + __expf(-z));
      }
}

// one wave per row: group top-2 sums -> top-4 groups -> flat top-8 -> normalized weights
__global__ __launch_bounds__(256) void route_kernel(const float* __restrict__ S,
                                                    const float* __restrict__ bias,
                                                    float* __restrict__ outw,
                                                    float* __restrict__ outi) {
  const int lane = threadIdx.x & 63;
  const int row  = blockIdx.x * 4 + (threadIdx.x >> 6);

  const float4 v4 = ((const float4*)(S + (size_t)row * N_EXP))[lane];
  const float4 b4 = ((const float4*)bias)[lane];
  float vals[4] = {v4.x, v4.y, v4.z, v4.w};                  // original (sigmoid)
  float s[4]    = {v4.x + b4.x, v4.y + b4.y, v4.z + b4.z, v4.w + b4.w};

  // per-lane top2 of its 4 selection scores
  float a  = fmaxf(s[0], s[1]), b_ = fminf(s[0], s[1]);
  float c  = fmaxf(s[2], s[3]), d  = fminf(s[2], s[3]);
  float t1 = fmaxf(a, c);
  float t2 = fmaxf(fminf(a, c), (a > c) ? b_ : d);
  // merge top2 across 8-lane group segments (group = 32 experts = 8 lanes)
#pragma unroll
  for (int off = 1; off < 8; off <<= 1) {
    const float o1 = __shfl_xor(t1, off);
    const float o2 = __shfl_xor(t2, off);
    const float n1 = fmaxf(t1, o1);
    const float n2 = fmaxf(fminf(t1, o1), (t1 > o1) ? t2 : o2);
    t1 = n1; t2 = n2;
  }
  const float gsum = t1 + t2;
  const int g = lane >> 3;
  float gs[8];
#pragma unroll
  for (int j = 0; j < 8; ++j) gs[j] = __shfl(gsum, j * 8);
  int rank = 0;
#pragma unroll
  for (int j = 0; j < 8; ++j)
    rank += (gs[j] > gs[g]) || (gs[j] == gs[g] && j < g);
  if (rank >= 4) { s[0] = s[1] = s[2] = s[3] = -INFINITY; }

  // flat top-8: wave argmax with (value desc, index asc) tie-break, 8 iterations
  float topw[8]; int topi[8];
  float wsum = 0.0f;
  const int col0 = lane * 4;
#pragma unroll
  for (int k = 0; k < 8; ++k) {
    float bv = s[0]; int bi = col0;
    if (s[1] > bv) { bv = s[1]; bi = col0 + 1; }
    if (s[2] > bv) { bv = s[2]; bi = col0 + 2; }
    if (s[3] > bv) { bv = s[3]; bi = col0 + 3; }
#pragma unroll
    for (int off = 32; off > 0; off >>= 1) {
      const float ov = __shfl_xor(bv, off);
      const int   oi = __shfl_xor(bi, off);
      if (ov > bv || (ov == bv && oi < bi)) { bv = ov; bi = oi; }
    }
    const int slot = bi & 3, owner = bi >> 2;
    const float cand = (slot == 0) ? vals[0] : (slot == 1) ? vals[1] : (slot == 2) ? vals[2] : vals[3];
    const float wv = __shfl(cand, owner);
    topw[k] = wv; topi[k] = bi; wsum += wv;
    if (lane == owner) {
      if      (slot == 0) s[0] = -INFINITY;
      else if (slot == 1) s[1] = -INFINITY;
      else if (slot == 2) s[2] = -INFINITY;
      else                s[3] = -INFINITY;
    }
  }
  const float sc = 2.5f / wsum;
  if (lane == 0) {
#pragma unroll
    for (int k = 0; k < 8; ++k) {
      outw[(size_t)row * 8 + k] = topw[k] * sc;
      outi[(size_t)row * 8 + k] = (float)topi[k];   // indices as float (flat fp32 compare)
    }
  }
}

extern "C" void kernel_launch(void* const* d_in, const int* in_sizes, int n_in,
                              void* d_out, int out_size, void* d_ws, size_t ws_size,
                              hipStream_t stream) {
  (void)in_sizes; (void)n_in; (void)out_size; (void)ws_size;
  const float* X  = (const float*)d_in[0];
  const float* Wt = (const float*)d_in[1];
  const float* b  = (const float*)d_in[2];

  // workspace layout: scores 16.78 MB | Wint (interleaved hi/lo fp16) 7.34 MB
  float*    scores = (float*)d_ws;
  _Float16* Wint   = (_Float16*)((char*)d_ws + (size_t)N_ROWS * N_EXP * 4);
  float* outw = (float*)d_out;                        // [N,8] weights
  float* outi = outw + (size_t)N_ROWS * 8;            // [N,8] indices (as float)

  wsplit_kernel<<<(N_EXP * K_DIM / 8) / 256, 256, 0, stream>>>(Wt, Wint);
  gemm_sig_kernel<<<(N_ROWS / BM) * (N_EXP / BN), 256, 0, stream>>>(X, Wint, scores);
  route_kernel<<<N_ROWS / 4, 256, 0, stream>>>(scores, b, outw, outi);
}

// Round 4
// 873.607 us; speedup vs baseline: 1.1220x; 1.1220x over previous
//
#include <hip/hip_runtime.h>
#include <math.h>

#define N_ROWS 16384
#define N_EXP  256
#define K_DIM  7168
#define BM 64
#define BK 32
#define KITERS (K_DIM / BK)   // 224

typedef __attribute__((ext_vector_type(4))) float     f32x4;
typedef __attribute__((ext_vector_type(8))) _Float16  f16x8;

// async global->LDS DMA, 16B per lane; LDS dest is wave-uniform base + lane*16
__device__ __forceinline__ void async16(const void* g, void* l) {
  __builtin_amdgcn_global_load_lds(
      (const __attribute__((address_space(1))) unsigned int*)g,
      (__attribute__((address_space(3))) unsigned int*)l, 16, 0, 0);
}

// split 8 fp32 values (scaled) into fp16 hi + fp16 residual fragments
__device__ __forceinline__ void split8(const float4 u, const float4 v, const float scale,
                                       f16x8& h, f16x8& l) {
  float f[8] = {u.x, u.y, u.z, u.w, v.x, v.y, v.z, v.w};
#pragma unroll
  for (int t = 0; t < 8; ++t) {
    const float sv = f[t] * scale;
    const _Float16 hh = (_Float16)sv;        // RN
    h[t] = hh;
    l[t] = (_Float16)(sv - (float)hh);       // exact fp32 residual, then RN to fp16
  }
}

// one-time W pre-split into FRAGMENT-MAJOR layout:
// per K-tile kb (32 k), chunk index = [hi:0 / lo:1]*1024 + q*256 + e  (16B chunks)
//   chunk holds fp16 of 64*W[e][kb*32 + q*8 .. +8] (hi or residual lo).
// -> a whole W K-tile is 32KB CONTIGUOUS: GEMM stages it with linear coalesced DMA.
// idx = o*256 + e (o = global k-octet 0..895): writes are 1KB-contiguous per wave.
__global__ __launch_bounds__(256) void wsplit_kernel(const float* __restrict__ W,
                                                     _Float16* __restrict__ Wf) {
  const int idx = blockIdx.x * 256 + threadIdx.x;   // 229376 threads
  const int o = idx >> 8, e = idx & 255;
  const float4* p = (const float4*)(W + (size_t)e * K_DIM + o * 8);
  f16x8 h, l;
  split8(p[0], p[1], 64.0f, h, l);
  const int kb = o >> 2, q = o & 3;
  _Float16* base = Wf + ((size_t)kb * 2048 + q * 256 + e) * 8;
  *(f16x8*)base          = h;       // hi plane
  *(f16x8*)(base + 8192) = l;       // lo plane (+1024 chunks)
}

// Fused: scores GEMM (BM=64 x all 256 experts) + sigmoid + per-row routing.
// C[m][e] = sigmoid( (1/1024) * sum_k (16*x[m][k]) * (64*W[e][k]) ), fp16-split 3-term MFMA.
//
// grid = 256 blocks (1/CU), 512 threads (8 waves: wr=wave&1 row-half, wc=wave>>1 col-quarter).
// X: DMA fp32 -> LDS, chunk slot j^(r&7) swizzle (verified r1; 2-way = free), split at consume.
// W: DMA from frag-major Wf -> LDS, fully linear/coalesced; B-frag ds_read contiguous 256B
//    per 16-lane group = conflict-free.
// Pipeline: triple buffer, ONE barrier per K-step, s_waitcnt vmcnt(5) (never 0 until tail):
//    2 tiles always in flight, DMA latency hides under a full iteration.
// Epilogue: scores+sigmoid -> LDS (overlays staging buffers), then each wave routes 8 rows
//    (verbatim round-1 route logic, source = LDS) -> no 16.8MB score round-trip, no 3rd kernel.
__global__ __launch_bounds__(512) void gemm_route_kernel(const float* __restrict__ X,
                                                         const _Float16* __restrict__ Wf,
                                                         const float* __restrict__ bias,
                                                         float* __restrict__ outw,
                                                         float* __restrict__ outi) {
  __shared__ __align__(16) char smem[122880];        // 120 KB
  float*    sX = (float*)smem;                       // 3 x 2048 floats (24 KB)
  _Float16* sW = (_Float16*)(smem + 24576);          // 3 x 16384 halves (96 KB)
  float*    sS = (float*)smem;                       // route phase: [64][260] (66.6 KB)

  const int tid  = threadIdx.x;
  const int lane = tid & 63;
  const int wave = tid >> 6;
  const int wr   = wave & 1;      // row half: 32 rows
  const int wc   = wave >> 1;     // col quarter: 64 cols
  const int ml   = lane & 15;
  const int quad = lane >> 4;
  const size_t rowBase = (size_t)blockIdx.x * BM;

  // X DMA role: LDS chunk c = tid -> row r=c>>3, slot j=c&7 holds global chunk j^(r&7)
  const int    xr = tid >> 3, xj = tid & 7;
  const float* xsrc = X + (rowBase + (size_t)xr) * K_DIM + ((xj ^ (xr & 7)) << 2);

  // A-frag fp32 chunk offsets (floats): row = wr*32 + tm*16 + ml, octet quad
  int xoffU[2], xoffV[2];
#pragma unroll
  for (int tm = 0; tm < 2; ++tm) {
    const int row = wr * 32 + tm * 16 + ml;
    const int sw  = row & 7;
    xoffU[tm] = (row * 8 + ((2 * quad)     ^ sw)) * 4;
    xoffV[tm] = (row * 8 + ((2 * quad + 1) ^ sw)) * 4;
  }
  // B-frag offsets (halves): chunk q*256 + e, e = wc*64 + tn*16 + ml
  int woffH[4];
#pragma unroll
  for (int tn = 0; tn < 4; ++tn)
    woffH[tn] = (quad * 256 + wc * 64 + tn * 16 + ml) * 8;

  f32x4 acc[2][4];
#pragma unroll
  for (int a = 0; a < 2; ++a)
#pragma unroll
    for (int b = 0; b < 4; ++b) acc[a][b] = (f32x4){0.f, 0.f, 0.f, 0.f};

  // stage one K-tile: 5 DMA instrs per thread (X:1, W:4), all coalesced
  auto stage = [&](int buf, int kb) {
    async16(xsrc + (size_t)kb * BK, sX + buf * 2048 + tid * 4);
    const _Float16* wsrc = Wf + (size_t)kb * 16384;
    _Float16*       wdst = sW + buf * 16384;
#pragma unroll
    for (int i = 0; i < 4; ++i) {
      const int c = i * 512 + tid;
      async16(wsrc + c * 8, wdst + c * 8);
    }
  };

  stage(0, 0);
  stage(1, 1);                                       // 10 DMAs in flight

  int cur = 0;
  for (int kb = 0; kb < KITERS; ++kb) {
    if (kb + 1 < KITERS) asm volatile("s_waitcnt vmcnt(5)" ::: "memory");  // tile kb done
    else                 asm volatile("s_waitcnt vmcnt(0)" ::: "memory");
    __builtin_amdgcn_s_barrier();
    asm volatile("" ::: "memory");
    if (kb + 2 < KITERS) {
      int nb = cur + 2; if (nb >= 3) nb -= 3;
      stage(nb, kb + 2);                             // back to 10 in flight
    }

    const float*    xb = sX + cur * 2048;
    const _Float16* wb = sW + cur * 16384;

    f16x8 bh[4], bl[4];
#pragma unroll
    for (int tn = 0; tn < 4; ++tn) {
      bh[tn] = *(const f16x8*)(wb + woffH[tn]);
      bl[tn] = *(const f16x8*)(wb + woffH[tn] + 8192);
    }
    f16x8 ah[2], al[2];
#pragma unroll
    for (int tm = 0; tm < 2; ++tm) {
      const float4 u = *(const float4*)(xb + xoffU[tm]);
      const float4 v = *(const float4*)(xb + xoffV[tm]);
      split8(u, v, 16.0f, ah[tm], al[tm]);
    }

#pragma unroll
    for (int tm = 0; tm < 2; ++tm)
#pragma unroll
      for (int tn = 0; tn < 4; ++tn) {
        acc[tm][tn] = __builtin_amdgcn_mfma_f32_16x16x32_f16(ah[tm], bh[tn], acc[tm][tn], 0, 0, 0);
        acc[tm][tn] = __builtin_amdgcn_mfma_f32_16x16x32_f16(ah[tm], bl[tn], acc[tm][tn], 0, 0, 0);
        acc[tm][tn] = __builtin_amdgcn_mfma_f32_16x16x32_f16(al[tm], bh[tn], acc[tm][tn], 0, 0, 0);
      }
    cur += 1; if (cur >= 3) cur = 0;
  }

  // ---- scores -> LDS with sigmoid (overlays staging buffers; all reads/DMAs done) ----
  __builtin_amdgcn_s_barrier();
  asm volatile("" ::: "memory");
  const float inv = 1.0f / 1024.0f;
#pragma unroll
  for (int tm = 0; tm < 2; ++tm)
#pragma unroll
    for (int tn = 0; tn < 4; ++tn)
#pragma unroll
      for (int rg = 0; rg < 4; ++rg) {
        const int r = wr * 32 + tm * 16 + quad * 4 + rg;   // C/D: row=(lane>>4)*4+reg
        const int c = wc * 64 + tn * 16 + ml;              //      col=lane&15
        const float z = acc[tm][tn][rg] * inv;
        sS[r * 260 + c] = 1.0f / (1.0f + __expf(-z));
      }
  asm volatile("s_waitcnt lgkmcnt(0)" ::: "memory");
  __builtin_amdgcn_s_barrier();
  asm volatile("" ::: "memory");

  // ---- per-row routing: wave handles rows wave*8 .. wave*8+7 ----
  const float4 b4 = ((const float4*)bias)[lane];
  for (int rr = 0; rr < 8; ++rr) {
    const int r = wave * 8 + rr;
    const float4 v4 = *(const float4*)(sS + r * 260 + lane * 4);
    float vals[4] = {v4.x, v4.y, v4.z, v4.w};              // original (sigmoid)
    float s[4]    = {v4.x + b4.x, v4.y + b4.y, v4.z + b4.z, v4.w + b4.w};

    // per-lane top2 of its 4 selection scores
    float a  = fmaxf(s[0], s[1]), b_ = fminf(s[0], s[1]);
    float c  = fmaxf(s[2], s[3]), d  = fminf(s[2], s[3]);
    float t1 = fmaxf(a, c);
    float t2 = fmaxf(fminf(a, c), (a > c) ? b_ : d);
    // merge top2 across 8-lane group segments (group = 32 experts = 8 lanes)
#pragma unroll
    for (int off = 1; off < 8; off <<= 1) {
      const float o1 = __shfl_xor(t1, off);
      const float o2 = __shfl_xor(t2, off);
      const float n1 = fmaxf(t1, o1);
      const float n2 = fmaxf(fminf(t1, o1), (t1 > o1) ? t2 : o2);
      t1 = n1; t2 = n2;
    }
    const float gsum = t1 + t2;
    const int g = lane >> 3;
    float gs[8];
#pragma unroll
    for (int j = 0; j < 8; ++j) gs[j] = __shfl(gsum, j * 8);
    int rank = 0;
#pragma unroll
    for (int j = 0; j < 8; ++j)
      rank += (gs[j] > gs[g]) || (gs[j] == gs[g] && j < g);
    if (rank >= 4) { s[0] = s[1] = s[2] = s[3] = -INFINITY; }

    // flat top-8: wave argmax with (value desc, index asc) tie-break, 8 iterations
    float topw[8]; int topi[8];
    float wsum = 0.0f;
    const int col0 = lane * 4;
#pragma unroll
    for (int k = 0; k < 8; ++k) {
      float bv = s[0]; int bi = col0;
      if (s[1] > bv) { bv = s[1]; bi = col0 + 1; }
      if (s[2] > bv) { bv = s[2]; bi = col0 + 2; }
      if (s[3] > bv) { bv = s[3]; bi = col0 + 3; }
#pragma unroll
      for (int off = 32; off > 0; off >>= 1) {
        const float ov = __shfl_xor(bv, off);
        const int   oi = __shfl_xor(bi, off);
        if (ov > bv || (ov == bv && oi < bi)) { bv = ov; bi = oi; }
      }
      const int slot = bi & 3, owner = bi >> 2;
      const float cand = (slot == 0) ? vals[0] : (slot == 1) ? vals[1] : (slot == 2) ? vals[2] : vals[3];
      const float wv = __shfl(cand, owner);
      topw[k] = wv; topi[k] = bi; wsum += wv;
      if (lane == owner) {
        if      (slot == 0) s[0] = -INFINITY;
        else if (slot == 1) s[1] = -INFINITY;
        else if (slot == 2) s[2] = -INFINITY;
        else                s[3] = -INFINITY;
      }
    }
    const float sc = 2.5f / wsum;
    if (lane == 0) {
      const size_t grow = rowBase + r;
#pragma unroll
      for (int k = 0; k < 8; ++k) {
        outw[grow * 8 + k] = topw[k] * sc;
        outi[grow * 8 + k] = (float)topi[k];   // indices as float (flat fp32 compare)
      }
    }
  }
}

extern "C" void kernel_launch(void* const* d_in, const int* in_sizes, int n_in,
                              void* d_out, int out_size, void* d_ws, size_t ws_size,
                              hipStream_t stream) {
  (void)in_sizes; (void)n_in; (void)out_size; (void)ws_size;
  const float* X  = (const float*)d_in[0];
  const float* Wt = (const float*)d_in[1];
  const float* b  = (const float*)d_in[2];

  // workspace: Wf (frag-major split fp16 hi/lo) 7.34 MB
  _Float16* Wf = (_Float16*)d_ws;
  float* outw = (float*)d_out;                        // [N,8] weights
  float* outi = outw + (size_t)N_ROWS * 8;            // [N,8] indices (as float)

  wsplit_kernel<<<(N_EXP * K_DIM / 8) / 256, 256, 0, stream>>>(Wt, Wf);
  gemm_route_kernel<<<N_ROWS / BM, 512, 0, stream>>>(X, Wf, b, outw, outi);
}